// Round 18
// baseline (110.969 us; speedup 1.0000x reference)
//
#include <hip/hip_runtime.h>
#include <math.h>

#define N_NODES 10000
#define E_EDGES 320000
#define EA      (E_EDGES + N_NODES)   // 330000 with self-loops
#define IN_DIM  128
#define HID     512                    // heads*dhead = 8*64
#define HEADS   8
#define OUT_DIM 32
#define NEG     0.2f
#define CAP     160                    // dst bucket capacity (max degree ~54)
#define CAPP    164                    // padded stride: 164 mod 32 = 4
#define NRB     628                    // 16-row blocks (628*16 >= N)
#define RB_SH   4096                   // shorts per 16-col W1 block: 2 seg x 16 chunks x 128

// k_pre block partition (256 threads each)
#define PWB  32                        // prep_w blocks
#define ZBK  40                        // zero cnt blocks
// k_sg block partition (512 threads each)
#define SCB  645                       // scatter: ceil(EA/512)

typedef __attribute__((ext_vector_type(8))) short bf16x8;
typedef __attribute__((ext_vector_type(4))) float f32x4;

__device__ __forceinline__ float leaky(float x){ return x > 0.f ? x : NEG * x; }

__device__ __forceinline__ unsigned short bf16rn(float x){
    unsigned int b = __float_as_uint(x);
    b += 0x7fffu + ((b >> 16) & 1u);
    return (unsigned short)(b >> 16);
}

__device__ __forceinline__ unsigned short f16bits(float x){
    _Float16 h = (_Float16)x;
    return __builtin_bit_cast(unsigned short, h);
}

__device__ __forceinline__ float f16val(unsigned short u){
    return (float)__builtin_bit_cast(_Float16, u);
}

// ------------- prologue: prep_w | zero cnt (x-prep folded into k_sg) --------
__global__ void k_pre(const float* __restrict__ W1, int* __restrict__ cnt,
                      unsigned short* __restrict__ Bt){
    int b = blockIdx.x, t = threadIdx.x;
    if (b < PWB){
        __shared__ float wsh[128 * 17];
        int nb = b;
        int j = t & 15, kr = t >> 4;
#pragma unroll
        for (int it = 0; it < 8; it++){
            int k = it * 16 + kr;
            wsh[k * 17 + j] = W1[(size_t)k * HID + nb * 16 + j];
        }
        __syncthreads();
        int l15 = t & 15, kk8 = t >> 4;
        unsigned short hi[8], lo[8];
#pragma unroll
        for (int el = 0; el < 8; el++){
            float f = wsh[(kk8 * 8 + el) * 17 + l15];
            hi[el] = bf16rn(f);
            lo[el] = bf16rn(f - __uint_as_float((unsigned)hi[el] << 16));
        }
        uint4 H, L;
        H.x = hi[0] | ((unsigned)hi[1] << 16); H.y = hi[2] | ((unsigned)hi[3] << 16);
        H.z = hi[4] | ((unsigned)hi[5] << 16); H.w = hi[6] | ((unsigned)hi[7] << 16);
        L.x = lo[0] | ((unsigned)lo[1] << 16); L.y = lo[2] | ((unsigned)lo[3] << 16);
        L.z = lo[4] | ((unsigned)lo[5] << 16); L.w = lo[6] | ((unsigned)lo[7] << 16);
        unsigned short* base = Bt + (size_t)nb * RB_SH;
        *reinterpret_cast<uint4*>(base + (kk8 * 16 + l15) * 8) = H;
        *reinterpret_cast<uint4*>(base + 2048 + (kk8 * 16 + l15) * 8) = L;
    } else {
        int i = (b - PWB) * 256 + t;
        if (i < N_NODES) cnt[i] = 0;
    }
}

// --- fused: bucket scatter || layer-1 MFMA GEMM (x converted in-kernel) ---
// Split GEMM: x@W = xhi*whi + xlo*whi + xhi*wlo (double-bf16, fp32-grade).
__launch_bounds__(512)
__global__ void k_sg(const int* __restrict__ eidx, int* __restrict__ cnt,
                     int* __restrict__ esrc,
                     const float* __restrict__ x,
                     const unsigned short* __restrict__ Bt,
                     const float* __restrict__ a1s, const float* __restrict__ a1d,
                     unsigned short* __restrict__ h1,
                     float* __restrict__ as1, float* __restrict__ ad1){
    __shared__ float xs[16 * 132];
    if (blockIdx.x < SCB){
        int e = blockIdx.x * 512 + threadIdx.x;
        if (e < EA){
            int d, s;
            if (e < E_EDGES){ s = eidx[e]; d = eidx[E_EDGES + e]; }
            else { s = d = e - E_EDGES; }
            int pos = atomicAdd(&cnt[d], 1);
            if (pos < CAP) esrc[d * CAP + pos] = s;
        }
        return;
    }
    int rb = blockIdx.x - SCB;                 // 0..627
    int t = threadIdx.x;
    {   // stage x tile (16 rows x 128 f32), zero-padded
        int r = t >> 5, c4 = t & 31;
        int row = rb * 16 + r;
        float4 v = make_float4(0.f, 0.f, 0.f, 0.f);
        if (row < N_NODES)
            v = *reinterpret_cast<const float4*>(x + (size_t)row * IN_DIM + c4 * 4);
        *reinterpret_cast<float4*>(&xs[r * 132 + c4 * 4]) = v;
    }
    __syncthreads();
    int by = t >> 6;                           // wave = head
    int lane = t & 63;
    int l15 = lane & 15, grp = lane >> 4;
    int m0 = rb * 16;
    int n0 = by * 64;
    // build A fragments in registers: element k = ks*32 + grp*8 + el of row l15
    bf16x8 a_hi[4], a_lo[4];
#pragma unroll
    for (int ks = 0; ks < 4; ks++){
        short hs[8], ls[8];
#pragma unroll
        for (int el = 0; el < 8; el++){
            float f = xs[l15 * 132 + ks * 32 + grp * 8 + el];
            unsigned short h = bf16rn(f);
            hs[el] = (short)h;
            ls[el] = (short)bf16rn(f - __uint_as_float((unsigned)h << 16));
        }
        a_hi[ks] = *reinterpret_cast<bf16x8*>(hs);
        a_lo[ks] = *reinterpret_cast<bf16x8*>(ls);
    }
    const unsigned short* bp = Bt + (size_t)(by * 4) * RB_SH + (size_t)lane * 8;
    f32x4 acc[4] = {};
#pragma unroll
    for (int ks = 0; ks < 4; ks++){
#pragma unroll
        for (int ns = 0; ns < 4; ns++){
            const unsigned short* bb = bp + (size_t)ns * RB_SH + ks * 512;
            bf16x8 b_hi = *reinterpret_cast<const bf16x8*>(bb);
            bf16x8 b_lo = *reinterpret_cast<const bf16x8*>(bb + 2048);
            acc[ns] = __builtin_amdgcn_mfma_f32_16x16x32_bf16(a_hi[ks], b_hi, acc[ns], 0, 0, 0);
            acc[ns] = __builtin_amdgcn_mfma_f32_16x16x32_bf16(a_lo[ks], b_hi, acc[ns], 0, 0, 0);
            acc[ns] = __builtin_amdgcn_mfma_f32_16x16x32_bf16(a_hi[ks], b_lo, acc[ns], 0, 0, 0);
        }
    }
    float vs[4] = {0.f, 0.f, 0.f, 0.f}, vd[4] = {0.f, 0.f, 0.f, 0.f};
#pragma unroll
    for (int ns = 0; ns < 4; ns++){
        int c = n0 + ns * 16 + l15;
        float a_s = a1s[c], a_d = a1d[c];
#pragma unroll
        for (int r = 0; r < 4; r++){
            float v = acc[ns][r];
            int rr = m0 + grp * 4 + r;
            if (rr < N_NODES) h1[(size_t)rr * HID + c] = f16bits(v);
            vs[r] += v * a_s; vd[r] += v * a_d;
        }
    }
#pragma unroll
    for (int r = 0; r < 4; r++){
#pragma unroll
        for (int off = 8; off >= 1; off >>= 1){
            vs[r] += __shfl_xor(vs[r], off);
            vd[r] += __shfl_xor(vd[r], off);
        }
    }
    if (l15 == 0){
#pragma unroll
        for (int r = 0; r < 4; r++){
            int rr = m0 + grp * 4 + r;
            if (rr < N_NODES){ as1[rr * HEADS + by] = vs[r]; ad1[rr * HEADS + by] = vd[r]; }
        }
    }
}

// ------ layer 1 aggregation: XCD-sharded head-pair, uint4 gather, 2-way edge split
// grid = 5000 blocks x 256 threads. gp = blockIdx&3 (head pair -> XCD pin),
// ng = blockIdx>>2. Block = 8 nodes x 32 threads; per node: 16 dim-owners
// (8 fp16 dims each) x 2 edge-parity halves, combined via shfl_xor(16).
__launch_bounds__(256)
__global__ void k_agg1(const unsigned short* __restrict__ h1,
                       const float* __restrict__ as1, const float* __restrict__ ad1,
                       const int* __restrict__ cnt, const int* __restrict__ esrc,
                       const float* __restrict__ b1, float* __restrict__ h1b){
    int gp = blockIdx.x & 3;
    int ng = blockIdx.x >> 2;
    int t  = threadIdx.x;
    int sub = t >> 5;                  // node within group of 8
    int tl  = t & 31;                  // lane within node group
    int l16 = tl & 15;                 // dim-owner
    int half = tl >> 4;                // edge-parity half
    int n = ng * 8 + sub;
    int g0 = gp * 2, g1 = g0 + 1;
    int c = cnt[n]; if (c > CAP) c = CAP;
    int beg = n * CAP;
    __shared__ float s_w0[8][CAPP];
    __shared__ float s_w1[8][CAPP];
    __shared__ unsigned s_off[8][CAPP];    // src*HID (short index)
    float adn0 = ad1[(n << 3) + g0];
    float adn1 = ad1[(n << 3) + g1];
    float pm0 = -INFINITY, pm1 = -INFINITY;
    for (int i = tl; i < c; i += 32){
        int s = esrc[beg + i];
        float lg0 = leaky(as1[(s << 3) + g0] + adn0);
        float lg1 = leaky(as1[(s << 3) + g1] + adn1);
        s_w0[sub][i] = lg0; s_w1[sub][i] = lg1;
        s_off[sub][i] = (unsigned)s << 9;
        pm0 = fmaxf(pm0, lg0); pm1 = fmaxf(pm1, lg1);
    }
#pragma unroll
    for (int off = 16; off >= 1; off >>= 1){
        pm0 = fmaxf(pm0, __shfl_xor(pm0, off));
        pm1 = fmaxf(pm1, __shfl_xor(pm1, off));
    }
    __syncthreads();
    for (int i = tl; i < c; i += 32){
        s_w0[sub][i] = __expf(s_w0[sub][i] - pm0);
        s_w1[sub][i] = __expf(s_w1[sub][i] - pm1);
    }
    __syncthreads();
    // gather: thread owns dims dbase..dbase+7 (head g0 if l16<8 else g1),
    // and edges of parity `half`.
    unsigned dbase = (unsigned)(gp * 128 + l16 * 8);
    const float* swp = (l16 >= 8) ? &s_w1[sub][0] : &s_w0[sub][0];
    const unsigned* sop = &s_off[sub][0];
    float ac[4][8] = {};
    float dn[4] = {};
    int i = half;
    for (; i + 6 < c; i += 8){
#pragma unroll
        for (int u = 0; u < 4; u++){
            int idx = i + 2 * u;
            float w = swp[idx];
            uint4 hv = *reinterpret_cast<const uint4*>(h1 + sop[idx] + dbase);
            ac[u][0] += w * f16val((unsigned short)(hv.x & 0xffffu));
            ac[u][1] += w * f16val((unsigned short)(hv.x >> 16));
            ac[u][2] += w * f16val((unsigned short)(hv.y & 0xffffu));
            ac[u][3] += w * f16val((unsigned short)(hv.y >> 16));
            ac[u][4] += w * f16val((unsigned short)(hv.z & 0xffffu));
            ac[u][5] += w * f16val((unsigned short)(hv.z >> 16));
            ac[u][6] += w * f16val((unsigned short)(hv.w & 0xffffu));
            ac[u][7] += w * f16val((unsigned short)(hv.w >> 16));
            dn[u] += w;
        }
    }
    for (; i < c; i += 2){
        float w = swp[i];
        uint4 hv = *reinterpret_cast<const uint4*>(h1 + sop[i] + dbase);
        ac[0][0] += w * f16val((unsigned short)(hv.x & 0xffffu));
        ac[0][1] += w * f16val((unsigned short)(hv.x >> 16));
        ac[0][2] += w * f16val((unsigned short)(hv.y & 0xffffu));
        ac[0][3] += w * f16val((unsigned short)(hv.y >> 16));
        ac[0][4] += w * f16val((unsigned short)(hv.z & 0xffffu));
        ac[0][5] += w * f16val((unsigned short)(hv.z >> 16));
        ac[0][6] += w * f16val((unsigned short)(hv.w & 0xffffu));
        ac[0][7] += w * f16val((unsigned short)(hv.w >> 16));
        dn[0] += w;
    }
    float den = (dn[0] + dn[1]) + (dn[2] + dn[3]);
    den += __shfl_xor(den, 16);
    float accj[8];
#pragma unroll
    for (int j = 0; j < 8; j++){
        float v = ((ac[0][j] + ac[1][j]) + (ac[2][j] + ac[3][j]));
        v += __shfl_xor(v, 16);
        accj[j] = v;
    }
    if (half == 0){
        float rd = 1.f / den;
        float4 bv0 = *reinterpret_cast<const float4*>(b1 + dbase);
        float4 bv1 = *reinterpret_cast<const float4*>(b1 + dbase + 4);
        float o[8];
#pragma unroll
        for (int j = 0; j < 8; j++){
            float v = accj[j] * rd;
            float bb = (j < 4) ? (&bv0.x)[j] : (&bv1.x)[j - 4];
            v += bb;
            o[j] = v > 0.f ? v : expm1f(v);
        }
        float4 o0, o1;
        o0.x = o[0]; o0.y = o[1]; o0.z = o[2]; o0.w = o[3];
        o1.x = o[4]; o1.y = o[5]; o1.z = o[6]; o1.w = o[7];
        *reinterpret_cast<float4*>(h1b + (size_t)n * HID + dbase) = o0;
        *reinterpret_cast<float4*>(h1b + (size_t)n * HID + dbase + 4) = o1;
    }
}

// ---------------- layer 2: h2 = h1b @ W2 (padded LDS, 4 cols/thread) ------------
__launch_bounds__(128)
__global__ void k_gemm2(const float* __restrict__ h1b, const float* __restrict__ W2,
                        const float* __restrict__ a2s, const float* __restrict__ a2d,
                        float* __restrict__ h2, float* __restrict__ as2,
                        float* __restrict__ ad2){
    __shared__ float hs[16 * 516];
    int t = threadIdx.x;
    int n0 = blockIdx.x * 16;
    const float4* src = reinterpret_cast<const float4*>(h1b + (size_t)n0 * HID);
    for (int i = t; i < 2048; i += 128){
        int r = i >> 7, c4 = i & 127;
        *reinterpret_cast<float4*>(&hs[r * 516 + c4 * 4]) = src[i];
    }
    __syncthreads();
    int nl = t >> 3, cg = t & 7, c0 = cg * 4;
    float a0 = 0.f, a1 = 0.f, a2 = 0.f, a3 = 0.f;
#pragma unroll 2
    for (int k4 = 0; k4 < 128; k4++){
        float4 hv = *reinterpret_cast<const float4*>(&hs[nl * 516 + k4 * 4]);
        float4 w0 = *reinterpret_cast<const float4*>(W2 + (k4 * 4 + 0) * OUT_DIM + c0);
        float4 w1 = *reinterpret_cast<const float4*>(W2 + (k4 * 4 + 1) * OUT_DIM + c0);
        float4 w2 = *reinterpret_cast<const float4*>(W2 + (k4 * 4 + 2) * OUT_DIM + c0);
        float4 w3 = *reinterpret_cast<const float4*>(W2 + (k4 * 4 + 3) * OUT_DIM + c0);
        a0 += hv.x * w0.x + hv.y * w1.x + hv.z * w2.x + hv.w * w3.x;
        a1 += hv.x * w0.y + hv.y * w1.y + hv.z * w2.y + hv.w * w3.y;
        a2 += hv.x * w0.z + hv.y * w1.z + hv.z * w2.z + hv.w * w3.z;
        a3 += hv.x * w0.w + hv.y * w1.w + hv.z * w2.w + hv.w * w3.w;
    }
    float4 o; o.x = a0; o.y = a1; o.z = a2; o.w = a3;
    *reinterpret_cast<float4*>(h2 + (size_t)(n0 + nl) * OUT_DIM + c0) = o;
    float4 s4 = *reinterpret_cast<const float4*>(a2s + c0);
    float4 d4 = *reinterpret_cast<const float4*>(a2d + c0);
    float vs = a0 * s4.x + a1 * s4.y + a2 * s4.z + a3 * s4.w;
    float vd = a0 * d4.x + a1 * d4.y + a2 * d4.z + a3 * d4.w;
#pragma unroll
    for (int off = 4; off >= 1; off >>= 1){
        vs += __shfl_xor(vs, off);
        vd += __shfl_xor(vd, off);
    }
    if (cg == 0){ as2[n0 + nl] = vs; ad2[n0 + nl] = vd; }
}

// ------ layer 2 aggregation: 8 edge-slots x 8 threads x float4 ------
__launch_bounds__(256)
__global__ void k_agg2(const float* __restrict__ h2, const float* __restrict__ as2,
                       const float* __restrict__ ad2, const int* __restrict__ cnt,
                       const int* __restrict__ esrc,
                       const float* __restrict__ b2, float* __restrict__ out){
    int wv = threadIdx.x >> 6;
    int lane = threadIdx.x & 63;
    int n = blockIdx.x * 4 + wv;
    __shared__ float    s_w[4][CAPP];
    __shared__ unsigned s_off[4][CAPP];
    int c = cnt[n]; if (c > CAP) c = CAP;
    int beg = n * CAP;
    float adn = ad2[n];
    float pm = -INFINITY;
    for (int i = lane; i < c; i += 64){
        int s = esrc[beg + i];
        float lg = leaky(as2[s] + adn);
        s_off[wv][i] = (unsigned)s * OUT_DIM;
        s_w[wv][i] = lg;
        pm = fmaxf(pm, lg);
    }
#pragma unroll
    for (int off = 32; off >= 1; off >>= 1)
        pm = fmaxf(pm, __shfl_xor(pm, off));
    __syncthreads();
    for (int i = lane; i < c; i += 64) s_w[wv][i] = __expf(s_w[wv][i] - pm);
    __syncthreads();
    int eslot = lane >> 3, dgrp = lane & 7, d0 = dgrp * 4;
    float4 acc = make_float4(0.f, 0.f, 0.f, 0.f);
    float den = 0.f;
    for (int i = eslot; i < c; i += 8){
        float w = s_w[wv][i];
        float4 hv = *reinterpret_cast<const float4*>(h2 + s_off[wv][i] + d0);
        acc.x += w * hv.x; acc.y += w * hv.y;
        acc.z += w * hv.z; acc.w += w * hv.w;
        den += w;
    }
#pragma unroll
    for (int off = 8; off <= 32; off <<= 1){
        acc.x += __shfl_xor(acc.x, off);
        acc.y += __shfl_xor(acc.y, off);
        acc.z += __shfl_xor(acc.z, off);
        acc.w += __shfl_xor(acc.w, off);
        den   += __shfl_xor(den, off);
    }
    if (eslot == 0){
        float rd = 1.f / den;
        float4 bv = *reinterpret_cast<const float4*>(b2 + d0);
        float4 o;
        o.x = acc.x * rd + bv.x; o.y = acc.y * rd + bv.y;
        o.z = acc.z * rd + bv.z; o.w = acc.w * rd + bv.w;
        *reinterpret_cast<float4*>(out + (size_t)n * OUT_DIM + d0) = o;
    }
}

// ---------------- launch ----------------
extern "C" void kernel_launch(void* const* d_in, const int* in_sizes, int n_in,
                              void* d_out, int out_size, void* d_ws, size_t ws_size,
                              hipStream_t stream){
    const float* x   = (const float*)d_in[0];
    const int*  eidx = (const int*)  d_in[1];
    const float* W1  = (const float*)d_in[2];
    const float* a1s = (const float*)d_in[3];
    const float* a1d = (const float*)d_in[4];
    const float* b1  = (const float*)d_in[5];
    const float* W2  = (const float*)d_in[6];
    const float* a2s = (const float*)d_in[7];
    const float* a2d = (const float*)d_in[8];
    const float* b2  = (const float*)d_in[9];
    float* out = (float*)d_out;

    char* ws = (char*)d_ws;
    size_t off = 0;
    auto alloc = [&](size_t bytes) -> void* {
        void* p = ws + off;
        off += (bytes + 255) & ~(size_t)255;
        return p;
    };
    unsigned short* h1 = (unsigned short*)alloc((size_t)N_NODES * HID * 2);
    float* h1b  = (float*)alloc((size_t)N_NODES * HID * 4);
    unsigned short* Bt = (unsigned short*)alloc((size_t)32 * RB_SH * 2);
    float* as1  = (float*)alloc((size_t)N_NODES * HEADS * 4);
    float* ad1  = (float*)alloc((size_t)N_NODES * HEADS * 4);
    float* h2   = (float*)alloc((size_t)N_NODES * OUT_DIM * 4);
    float* vs2  = (float*)alloc((size_t)N_NODES * 4);
    float* vd2  = (float*)alloc((size_t)N_NODES * 4);
    int* cnt    = (int*)alloc((size_t)N_NODES * 4);
    int* esrc   = (int*)alloc((size_t)N_NODES * CAP * 4);   // 6.4 MB buckets

    k_pre <<<PWB + ZBK, 256, 0, stream>>>(W1, cnt, Bt);
    k_sg  <<<SCB + NRB, 512, 0, stream>>>(eidx, cnt, esrc, x, Bt, a1s, a1d,
                                          h1, as1, ad1);
    k_agg1<<<(N_NODES / 8) * 4, 256, 0, stream>>>(h1, as1, ad1, cnt, esrc, b1, h1b);
    k_gemm2<<<N_NODES / 16, 128, 0, stream>>>(h1b, W2, a2s, a2d, h2, vs2, vd2);
    k_agg2<<<N_NODES / 4, 256, 0, stream>>>(h2, vs2, vd2, cnt, esrc, b2, out);
}

// Round 19
// 109.014 us; speedup vs baseline: 1.0179x; 1.0179x over previous
//
#include <hip/hip_runtime.h>
#include <math.h>

#define N_NODES 10000
#define E_EDGES 320000
#define EA      (E_EDGES + N_NODES)   // 330000 with self-loops
#define IN_DIM  128
#define HID     512                    // heads*dhead = 8*64
#define HEADS   8
#define OUT_DIM 32
#define NEG     0.2f
#define CAP     160                    // dst bucket capacity (max degree ~54)
#define CAPP    164                    // padded stride: 164 mod 32 = 4
#define N_PAD   10048                  // 628*16
#define NRB     628                    // 16-row blocks
#define RB_SH   4096                   // shorts per 16-row block: 2 seg x 16 chunks x 128

// k_pre block partition (256 threads each)
#define PWB  32                        // prep_w blocks
#define ZBK  40                        // zero cnt blocks
// k_sg block partition (512 threads each)
#define SCB  645                       // scatter: ceil(EA/512)

typedef __attribute__((ext_vector_type(8))) short bf16x8;
typedef __attribute__((ext_vector_type(4))) float f32x4;
typedef __attribute__((ext_vector_type(2))) _Float16 h2v;

__device__ __forceinline__ float leaky(float x){ return x > 0.f ? x : NEG * x; }

__device__ __forceinline__ unsigned short bf16rn(float x){
    unsigned int b = __float_as_uint(x);
    b += 0x7fffu + ((b >> 16) & 1u);
    return (unsigned short)(b >> 16);
}

__device__ __forceinline__ unsigned short f16bits(float x){
    _Float16 h = (_Float16)x;
    return __builtin_bit_cast(unsigned short, h);
}

__device__ __forceinline__ float f16val(unsigned short u){
    return (float)__builtin_bit_cast(_Float16, u);
}

// ------------- fused prologue: prep_x | prep_w | zero cnt --------
__global__ void k_pre(const float* __restrict__ x, const float* __restrict__ W1,
                      int* __restrict__ cnt,
                      unsigned short* __restrict__ Ax, unsigned short* __restrict__ Bt){
    int b = blockIdx.x, t = threadIdx.x;
    if (b < NRB){
        __shared__ float xs[16 * 132];
        int rb = b;
#pragma unroll
        for (int j = 0; j < 2; j++){
            int idx = t + j * 256;             // 0..511
            int r = idx >> 5, c4 = idx & 31;
            int row = rb * 16 + r;
            float4 v = make_float4(0.f, 0.f, 0.f, 0.f);
            if (row < N_NODES)
                v = *reinterpret_cast<const float4*>(x + (size_t)row * IN_DIM + c4 * 4);
            *reinterpret_cast<float4*>(&xs[r * 132 + c4 * 4]) = v;
        }
        __syncthreads();
        int l15 = t & 15, kk8 = t >> 4;
        unsigned short hi[8], lo[8];
#pragma unroll
        for (int el = 0; el < 8; el++){
            float f = xs[l15 * 132 + kk8 * 8 + el];
            hi[el] = bf16rn(f);
            lo[el] = bf16rn(f - __uint_as_float((unsigned)hi[el] << 16));
        }
        uint4 H, L;
        H.x = hi[0] | ((unsigned)hi[1] << 16); H.y = hi[2] | ((unsigned)hi[3] << 16);
        H.z = hi[4] | ((unsigned)hi[5] << 16); H.w = hi[6] | ((unsigned)hi[7] << 16);
        L.x = lo[0] | ((unsigned)lo[1] << 16); L.y = lo[2] | ((unsigned)lo[3] << 16);
        L.z = lo[4] | ((unsigned)lo[5] << 16); L.w = lo[6] | ((unsigned)lo[7] << 16);
        unsigned short* base = Ax + (size_t)rb * RB_SH;
        *reinterpret_cast<uint4*>(base + (kk8 * 16 + l15) * 8) = H;
        *reinterpret_cast<uint4*>(base + 2048 + (kk8 * 16 + l15) * 8) = L;
    } else if (b < NRB + PWB){
        __shared__ float wsh[128 * 17];
        int nb = b - NRB;
        int j = t & 15, kr = t >> 4;
#pragma unroll
        for (int it = 0; it < 8; it++){
            int k = it * 16 + kr;
            wsh[k * 17 + j] = W1[(size_t)k * HID + nb * 16 + j];
        }
        __syncthreads();
        int l15 = t & 15, kk8 = t >> 4;
        unsigned short hi[8], lo[8];
#pragma unroll
        for (int el = 0; el < 8; el++){
            float f = wsh[(kk8 * 8 + el) * 17 + l15];
            hi[el] = bf16rn(f);
            lo[el] = bf16rn(f - __uint_as_float((unsigned)hi[el] << 16));
        }
        uint4 H, L;
        H.x = hi[0] | ((unsigned)hi[1] << 16); H.y = hi[2] | ((unsigned)hi[3] << 16);
        H.z = hi[4] | ((unsigned)hi[5] << 16); H.w = hi[6] | ((unsigned)hi[7] << 16);
        L.x = lo[0] | ((unsigned)lo[1] << 16); L.y = lo[2] | ((unsigned)lo[3] << 16);
        L.z = lo[4] | ((unsigned)lo[5] << 16); L.w = lo[6] | ((unsigned)lo[7] << 16);
        unsigned short* base = Bt + (size_t)nb * RB_SH;
        *reinterpret_cast<uint4*>(base + (kk8 * 16 + l15) * 8) = H;
        *reinterpret_cast<uint4*>(base + 2048 + (kk8 * 16 + l15) * 8) = L;
    } else {
        int i = (b - NRB - PWB) * 256 + t;
        if (i < N_NODES) cnt[i] = 0;
    }
}

// --------- fused: bucket scatter || layer-1 MFMA GEMM (1 rb x 8 heads/block) ----
__launch_bounds__(512)
__global__ void k_sg(const int* __restrict__ eidx, int* __restrict__ cnt,
                     int* __restrict__ esrc,
                     const unsigned short* __restrict__ Ax,
                     const unsigned short* __restrict__ Bt,
                     const float* __restrict__ a1s, const float* __restrict__ a1d,
                     unsigned short* __restrict__ h1,
                     float* __restrict__ as1, float* __restrict__ ad1){
    if (blockIdx.x < SCB){
        int e = blockIdx.x * 512 + threadIdx.x;
        if (e < EA){
            int d, s;
            if (e < E_EDGES){ s = eidx[e]; d = eidx[E_EDGES + e]; }
            else { s = d = e - E_EDGES; }
            int pos = atomicAdd(&cnt[d], 1);
            if (pos < CAP) esrc[d * CAP + pos] = s;
        }
        return;
    }
    int rb = blockIdx.x - SCB;                 // 0..627
    int by = threadIdx.x >> 6;                 // wave = head
    int lane = threadIdx.x & 63;
    int l15 = lane & 15, grp = lane >> 4;
    int m0 = rb * 16;
    int n0 = by * 64;
    const unsigned short* ap = Ax + (size_t)rb * RB_SH + (size_t)lane * 8;
    bf16x8 a_hi[4], a_lo[4];
#pragma unroll
    for (int ks = 0; ks < 4; ks++){
        a_hi[ks] = *reinterpret_cast<const bf16x8*>(ap + ks * 512);
        a_lo[ks] = *reinterpret_cast<const bf16x8*>(ap + 2048 + ks * 512);
    }
    const unsigned short* bp = Bt + (size_t)(by * 4) * RB_SH + (size_t)lane * 8;
    f32x4 acc[4] = {};
#pragma unroll
    for (int ks = 0; ks < 4; ks++){
#pragma unroll
        for (int ns = 0; ns < 4; ns++){
            const unsigned short* bb = bp + (size_t)ns * RB_SH + ks * 512;
            bf16x8 b_hi = *reinterpret_cast<const bf16x8*>(bb);
            bf16x8 b_lo = *reinterpret_cast<const bf16x8*>(bb + 2048);
            acc[ns] = __builtin_amdgcn_mfma_f32_16x16x32_bf16(a_hi[ks], b_hi, acc[ns], 0, 0, 0);
            acc[ns] = __builtin_amdgcn_mfma_f32_16x16x32_bf16(a_lo[ks], b_hi, acc[ns], 0, 0, 0);
            acc[ns] = __builtin_amdgcn_mfma_f32_16x16x32_bf16(a_hi[ks], b_lo, acc[ns], 0, 0, 0);
        }
    }
    float vs[4] = {0.f, 0.f, 0.f, 0.f}, vd[4] = {0.f, 0.f, 0.f, 0.f};
#pragma unroll
    for (int ns = 0; ns < 4; ns++){
        int c = n0 + ns * 16 + l15;
        float a_s = a1s[c], a_d = a1d[c];
#pragma unroll
        for (int r = 0; r < 4; r++){
            float v = acc[ns][r];
            int rr = m0 + grp * 4 + r;
            if (rr < N_NODES) h1[(size_t)rr * HID + c] = f16bits(v);
            vs[r] += v * a_s; vd[r] += v * a_d;
        }
    }
#pragma unroll
    for (int r = 0; r < 4; r++){
#pragma unroll
        for (int off = 8; off >= 1; off >>= 1){
            vs[r] += __shfl_xor(vs[r], off);
            vd[r] += __shfl_xor(vd[r], off);
        }
    }
    if (l15 == 0){
#pragma unroll
        for (int r = 0; r < 4; r++){
            int rr = m0 + grp * 4 + r;
            if (rr < N_NODES){ as1[rr * HEADS + by] = vs[r]; ad1[rr * HEADS + by] = vd[r]; }
        }
    }
}

// ------ layer 1 aggregation: XCD-sharded head-pair + uint4 + paired fdot2 ------
// grid = 5000 blocks x 128 threads. gp = blockIdx&3 (head pair -> XCD pin),
// ng = blockIdx>>2. Block = 8 nodes x 16 threads; thread owns 8 fp16 dims.
// Inner loop: edges in pairs, v_dot2_f32_f16 accumulation (1 pack + 1 dot2
// per dim-pair vs 2 cvt + 2 fma). Weights pass through fp16; den uses the
// same fp16-rounded weights, so the softmax stays exactly convex.
__launch_bounds__(128)
__global__ void k_agg1(const unsigned short* __restrict__ h1,
                       const float* __restrict__ as1, const float* __restrict__ ad1,
                       const int* __restrict__ cnt, const int* __restrict__ esrc,
                       const float* __restrict__ b1, float* __restrict__ h1b){
    int gp = blockIdx.x & 3;
    int ng = blockIdx.x >> 2;
    int t  = threadIdx.x;
    int sub = t >> 4;                  // node within group of 8
    int tl  = t & 15;                  // lane within node sub-group
    int n = ng * 8 + sub;
    int g0 = gp * 2, g1 = g0 + 1;
    int c = cnt[n]; if (c > CAP) c = CAP;
    int beg = n * CAP;
    __shared__ float s_w0[8][CAPP];
    __shared__ float s_w1[8][CAPP];
    __shared__ unsigned s_off[8][CAPP];    // src*HID (short index)
    float adn0 = ad1[(n << 3) + g0];
    float adn1 = ad1[(n << 3) + g1];
    float pm0 = -INFINITY, pm1 = -INFINITY;
    for (int i = tl; i < c; i += 16){
        int s = esrc[beg + i];
        float lg0 = leaky(as1[(s << 3) + g0] + adn0);
        float lg1 = leaky(as1[(s << 3) + g1] + adn1);
        s_w0[sub][i] = lg0; s_w1[sub][i] = lg1;
        s_off[sub][i] = (unsigned)s << 9;
        pm0 = fmaxf(pm0, lg0); pm1 = fmaxf(pm1, lg1);
    }
#pragma unroll
    for (int off = 8; off >= 1; off >>= 1){
        pm0 = fmaxf(pm0, __shfl_xor(pm0, off, 16));
        pm1 = fmaxf(pm1, __shfl_xor(pm1, off, 16));
    }
    __syncthreads();
    for (int i = tl; i < c; i += 16){
        s_w0[sub][i] = __expf(s_w0[sub][i] - pm0);
        s_w1[sub][i] = __expf(s_w1[sub][i] - pm1);
    }
    __syncthreads();
    // gather: thread owns dims dbase..dbase+7 (head g0 if tl<8 else g1)
    unsigned dbase = (unsigned)(gp * 128 + tl * 8);
    const float* swp = (tl >= 8) ? &s_w1[sub][0] : &s_w0[sub][0];
    const unsigned* sop = &s_off[sub][0];
    float ac[2][8] = {};
    float dn = 0.f;
    int i = 0;
    for (; i + 3 < c; i += 4){
#pragma unroll
        for (int p = 0; p < 2; p++){
            int ia = i + 2 * p, ib = ia + 1;
            float wa = swp[ia], wb = swp[ib];
            uint4 va = *reinterpret_cast<const uint4*>(h1 + sop[ia] + dbase);
            uint4 vb = *reinterpret_cast<const uint4*>(h1 + sop[ib] + dbase);
            _Float16 wah = (_Float16)wa, wbh = (_Float16)wb;
            h2v wpk; wpk[0] = wah; wpk[1] = wbh;
            dn += (float)wah + (float)wbh;
            const unsigned* pa = &va.x;
            const unsigned* pb = &vb.x;
#pragma unroll
            for (int d = 0; d < 4; d++){
                h2v ha = __builtin_bit_cast(h2v, pa[d]);
                h2v hb = __builtin_bit_cast(h2v, pb[d]);
                h2v e0; e0[0] = ha[0]; e0[1] = hb[0];
                h2v e1; e1[0] = ha[1]; e1[1] = hb[1];
                ac[p][2 * d]     = __builtin_amdgcn_fdot2(e0, wpk, ac[p][2 * d], false);
                ac[p][2 * d + 1] = __builtin_amdgcn_fdot2(e1, wpk, ac[p][2 * d + 1], false);
            }
        }
    }
    for (; i < c; i++){
        _Float16 wh = (_Float16)swp[i];
        float wf = (float)wh;
        uint4 hv = *reinterpret_cast<const uint4*>(h1 + sop[i] + dbase);
        dn += wf;
        const unsigned* pv = &hv.x;
#pragma unroll
        for (int d = 0; d < 4; d++){
            h2v hh = __builtin_bit_cast(h2v, pv[d]);
            ac[0][2 * d]     += wf * (float)hh[0];
            ac[0][2 * d + 1] += wf * (float)hh[1];
        }
    }
    float rd = 1.f / dn;
    float4 bv0 = *reinterpret_cast<const float4*>(b1 + dbase);
    float4 bv1 = *reinterpret_cast<const float4*>(b1 + dbase + 4);
    float o[8];
#pragma unroll
    for (int j = 0; j < 8; j++){
        float v = (ac[0][j] + ac[1][j]) * rd;
        float bb = (j < 4) ? (&bv0.x)[j] : (&bv1.x)[j - 4];
        v += bb;
        o[j] = v > 0.f ? v : expm1f(v);
    }
    float4 o0, o1;
    o0.x = o[0]; o0.y = o[1]; o0.z = o[2]; o0.w = o[3];
    o1.x = o[4]; o1.y = o[5]; o1.z = o[6]; o1.w = o[7];
    *reinterpret_cast<float4*>(h1b + (size_t)n * HID + dbase) = o0;
    *reinterpret_cast<float4*>(h1b + (size_t)n * HID + dbase + 4) = o1;
}

// ---------------- layer 2: h2 = h1b @ W2 (padded LDS, 4 cols/thread) ------------
__launch_bounds__(128)
__global__ void k_gemm2(const float* __restrict__ h1b, const float* __restrict__ W2,
                        const float* __restrict__ a2s, const float* __restrict__ a2d,
                        float* __restrict__ h2, float* __restrict__ as2,
                        float* __restrict__ ad2){
    __shared__ float hs[16 * 516];
    int t = threadIdx.x;
    int n0 = blockIdx.x * 16;
    const float4* src = reinterpret_cast<const float4*>(h1b + (size_t)n0 * HID);
    for (int i = t; i < 2048; i += 128){
        int r = i >> 7, c4 = i & 127;
        *reinterpret_cast<float4*>(&hs[r * 516 + c4 * 4]) = src[i];
    }
    __syncthreads();
    int nl = t >> 3, cg = t & 7, c0 = cg * 4;
    float a0 = 0.f, a1 = 0.f, a2 = 0.f, a3 = 0.f;
#pragma unroll 2
    for (int k4 = 0; k4 < 128; k4++){
        float4 hv = *reinterpret_cast<const float4*>(&hs[nl * 516 + k4 * 4]);
        float4 w0 = *reinterpret_cast<const float4*>(W2 + (k4 * 4 + 0) * OUT_DIM + c0);
        float4 w1 = *reinterpret_cast<const float4*>(W2 + (k4 * 4 + 1) * OUT_DIM + c0);
        float4 w2 = *reinterpret_cast<const float4*>(W2 + (k4 * 4 + 2) * OUT_DIM + c0);
        float4 w3 = *reinterpret_cast<const float4*>(W2 + (k4 * 4 + 3) * OUT_DIM + c0);
        a0 += hv.x * w0.x + hv.y * w1.x + hv.z * w2.x + hv.w * w3.x;
        a1 += hv.x * w0.y + hv.y * w1.y + hv.z * w2.y + hv.w * w3.y;
        a2 += hv.x * w0.z + hv.y * w1.z + hv.z * w2.z + hv.w * w3.z;
        a3 += hv.x * w0.w + hv.y * w1.w + hv.z * w2.w + hv.w * w3.w;
    }
    float4 o; o.x = a0; o.y = a1; o.z = a2; o.w = a3;
    *reinterpret_cast<float4*>(h2 + (size_t)(n0 + nl) * OUT_DIM + c0) = o;
    float4 s4 = *reinterpret_cast<const float4*>(a2s + c0);
    float4 d4 = *reinterpret_cast<const float4*>(a2d + c0);
    float vs = a0 * s4.x + a1 * s4.y + a2 * s4.z + a3 * s4.w;
    float vd = a0 * d4.x + a1 * d4.y + a2 * d4.z + a3 * d4.w;
#pragma unroll
    for (int off = 4; off >= 1; off >>= 1){
        vs += __shfl_xor(vs, off);
        vd += __shfl_xor(vd, off);
    }
    if (cg == 0){ as2[n0 + nl] = vs; ad2[n0 + nl] = vd; }
}

// ------ layer 2 aggregation: 8 edge-slots x 8 threads x float4 ------
__launch_bounds__(256)
__global__ void k_agg2(const float* __restrict__ h2, const float* __restrict__ as2,
                       const float* __restrict__ ad2, const int* __restrict__ cnt,
                       const int* __restrict__ esrc,
                       const float* __restrict__ b2, float* __restrict__ out){
    int wv = threadIdx.x >> 6;
    int lane = threadIdx.x & 63;
    int n = blockIdx.x * 4 + wv;
    __shared__ float    s_w[4][CAPP];
    __shared__ unsigned s_off[4][CAPP];
    int c = cnt[n]; if (c > CAP) c = CAP;
    int beg = n * CAP;
    float adn = ad2[n];
    float pm = -INFINITY;
    for (int i = lane; i < c; i += 64){
        int s = esrc[beg + i];
        float lg = leaky(as2[s] + adn);
        s_off[wv][i] = (unsigned)s * OUT_DIM;
        s_w[wv][i] = lg;
        pm = fmaxf(pm, lg);
    }
#pragma unroll
    for (int off = 32; off >= 1; off >>= 1)
        pm = fmaxf(pm, __shfl_xor(pm, off));
    __syncthreads();
    for (int i = lane; i < c; i += 64) s_w[wv][i] = __expf(s_w[wv][i] - pm);
    __syncthreads();
    int eslot = lane >> 3, dgrp = lane & 7, d0 = dgrp * 4;
    float4 acc = make_float4(0.f, 0.f, 0.f, 0.f);
    float den = 0.f;
    for (int i = eslot; i < c; i += 8){
        float w = s_w[wv][i];
        float4 hv = *reinterpret_cast<const float4*>(h2 + s_off[wv][i] + d0);
        acc.x += w * hv.x; acc.y += w * hv.y;
        acc.z += w * hv.z; acc.w += w * hv.w;
        den += w;
    }
#pragma unroll
    for (int off = 8; off <= 32; off <<= 1){
        acc.x += __shfl_xor(acc.x, off);
        acc.y += __shfl_xor(acc.y, off);
        acc.z += __shfl_xor(acc.z, off);
        acc.w += __shfl_xor(acc.w, off);
        den   += __shfl_xor(den, off);
    }
    if (eslot == 0){
        float rd = 1.f / den;
        float4 bv = *reinterpret_cast<const float4*>(b2 + d0);
        float4 o;
        o.x = acc.x * rd + bv.x; o.y = acc.y * rd + bv.y;
        o.z = acc.z * rd + bv.z; o.w = acc.w * rd + bv.w;
        *reinterpret_cast<float4*>(out + (size_t)n * OUT_DIM + d0) = o;
    }
}

// ---------------- launch ----------------
extern "C" void kernel_launch(void* const* d_in, const int* in_sizes, int n_in,
                              void* d_out, int out_size, void* d_ws, size_t ws_size,
                              hipStream_t stream){
    const float* x   = (const float*)d_in[0];
    const int*  eidx = (const int*)  d_in[1];
    const float* W1  = (const float*)d_in[2];
    const float* a1s = (const float*)d_in[3];
    const float* a1d = (const float*)d_in[4];
    const float* b1  = (const float*)d_in[5];
    const float* W2  = (const float*)d_in[6];
    const float* a2s = (const float*)d_in[7];
    const float* a2d = (const float*)d_in[8];
    const float* b2  = (const float*)d_in[9];
    float* out = (float*)d_out;

    char* ws = (char*)d_ws;
    size_t off = 0;
    auto alloc = [&](size_t bytes) -> void* {
        void* p = ws + off;
        off += (bytes + 255) & ~(size_t)255;
        return p;
    };
    unsigned short* h1 = (unsigned short*)alloc((size_t)N_NODES * HID * 2);
    float* h1b  = (float*)alloc((size_t)N_NODES * HID * 4);
    unsigned short* Bt = (unsigned short*)alloc((size_t)32 * RB_SH * 2);
    float* as1  = (float*)alloc((size_t)N_NODES * HEADS * 4);
    float* ad1  = (float*)alloc((size_t)N_NODES * HEADS * 4);
    float* h2   = (float*)alloc((size_t)N_NODES * OUT_DIM * 4);
    float* vs2  = (float*)alloc((size_t)N_NODES * 4);
    float* vd2  = (float*)alloc((size_t)N_NODES * 4);
    int* cnt    = (int*)alloc((size_t)N_NODES * 4);
    int* esrc   = (int*)alloc((size_t)N_NODES * CAP * 4);   // 6.4 MB buckets
    // Ax aliases h1b (5.1 MB < 20.5 MB): k_sg consumes Ax before agg1 writes h1b
    unsigned short* Ax = (unsigned short*)h1b;

    k_pre <<<NRB + PWB + ZBK, 256, 0, stream>>>(x, W1, cnt, Ax, Bt);
    k_sg  <<<SCB + NRB, 512, 0, stream>>>(eidx, cnt, esrc, Ax, Bt, a1s, a1d,
                                          h1, as1, ad1);
    k_agg1<<<(N_NODES / 8) * 4, 128, 0, stream>>>(h1, as1, ad1, cnt, esrc, b1, h1b);
    k_gemm2<<<N_NODES / 16, 128, 0, stream>>>(h1b, W2, a2s, a2d, h2, vs2, vd2);
    k_agg2<<<N_NODES / 4, 256, 0, stream>>>(h2, vs2, vd2, cnt, esrc, b2, out);
}